// Round 17
// baseline (685.620 us; speedup 1.0000x reference)
//
#include <hip/hip_runtime.h>
#include <math.h>

#define HH 192
#define WW 192
#define HWP (192*192)
#define BB 4
#define CF 64
#define NC 7
#define OO 64
#define NTOT (BB*HWP)          // 147456
#define PBLK2 (HWP/128)        // 288

// bank swizzle: XOR bits 2-4 of column with row bits 2-4 (keeps float4 align)
#define SW(r, c) ((c) ^ ((((r) >> 2) & 7) << 2))

typedef float f32x4 __attribute__((ext_vector_type(4)));

// ---------------- vectorized depthwise conv: 4 outputs/thread -------------
template<int k>
__global__ __launch_bounds__(256)
void dwv_kernel(const float* __restrict__ fea, const float* __restrict__ w,
                const float* __restrict__ bias, float* __restrict__ out) {
    constexpr int pad = k / 2;
    int idx = blockIdx.x * 256 + threadIdx.x;      // over B*CF*HH*48
    int xq = idx % 48;
    int x0 = xq * 4;
    int hpos = (idx / 48) % HH;
    int plane = idx / (48 * HH);
    int c = plane % CF;
    const float* f = fea + (size_t)plane * HWP;

    float wk[k * k];
#pragma unroll
    for (int i = 0; i < k * k; ++i) wk[i] = w[c * k * k + i];

    float acc0 = 0.f, acc1 = 0.f, acc2 = 0.f, acc3 = 0.f;
#pragma unroll
    for (int dy = 0; dy < k; ++dy) {
        int y = hpos + dy - pad;
        if (y < 0 || y >= HH) continue;
        const float* row = f + y * WW;
        float4 q0 = (x0 >= 4) ? *(const float4*)(row + x0 - 4) : make_float4(0.f, 0.f, 0.f, 0.f);
        float4 q1 = *(const float4*)(row + x0);
        float4 q2 = (x0 + 4 < WW) ? *(const float4*)(row + x0 + 4) : make_float4(0.f, 0.f, 0.f, 0.f);
        float wnd[8] = {q0.z, q0.w, q1.x, q1.y, q1.z, q1.w, q2.x, q2.y};
#pragma unroll
        for (int dx = 0; dx < k; ++dx) {
            float wt = wk[dy * k + dx];
            acc0 += wnd[0 + dx + 2 - pad] * wt;
            acc1 += wnd[1 + dx + 2 - pad] * wt;
            acc2 += wnd[2 + dx + 2 - pad] * wt;
            acc3 += wnd[3 + dx + 2 - pad] * wt;
        }
    }
    float b = bias[c];
    float4 o = make_float4(acc0 + b, acc1 + b, acc2 + b, acc3 + b);
    *(float4*)(out + (size_t)plane * HWP + hpos * WW + x0) = o;
}

// ---------------- generic small transpose ----------------
__global__ void transpose_kernel(const float* __restrict__ in, float* __restrict__ out,
                                 int rows, int cols) {
    int idx = blockIdx.x * 256 + threadIdx.x;
    if (idx >= rows * cols) return;
    int r = idx / cols, c = idx % cols;
    out[c * rows + r] = in[idx];
}

// ---------------- k1 weight fold: pw_w' = pw_w*diag(w0), b' = pw_b+pw_w@b0
__global__ void k1_fold_kernel(const float* __restrict__ pw_w, const float* __restrict__ pw_b,
                               const float* __restrict__ dw_w0, const float* __restrict__ dw_b0,
                               float* __restrict__ pw_wf, float* __restrict__ pw_bf) {
    int i = blockIdx.x * 256 + threadIdx.x;
    if (i < 21 * 64) pw_wf[i] = pw_w[i] * dw_w0[i & 63];
    if (i < 21) {
        float s = pw_b[i];
        for (int c = 0; c < 64; ++c) s += pw_w[i * 64 + c] * dw_b0[c];
        pw_bf[i] = s;
    }
}

// ---------------- fully fused branch kernel, N=128, 512 threads -----------
// Round-16: 512 threads restore 4 threads/px sampling + 24 waves/CU
// (3 blocks x 8 waves at 51.2KB LDS); 4ch x 4px microtile; Bs time-shared
// {dw tile -> parked triplets -> samples} with XOR bank swizzle (kills the
// 8.2M park-write conflicts of rounds 14/15).
template<int k>
__global__ __launch_bounds__(512)
void branch_fused_kernel(const float* __restrict__ pw_w, const float* __restrict__ pw_b,
                         const float* __restrict__ dw, const float* __restrict__ inputs,
                         const float* __restrict__ dcn_wt, const float* __restrict__ dcn_b,
                         float* __restrict__ outbuf, int t_slot) {
    constexpr int K = k * k;
    constexpr int TT = NC * K;
    constexpr int pad = k / 2;
    __shared__ float As[64][68];
    __shared__ float Bs[64][132];
    int nb0 = blockIdx.x * 128;
    int b = nb0 / HWP, p0 = nb0 % HWP;
    int tid = threadIdx.x;
    int tm = (tid & 15) * 4;            // 4-channel group
    int tn = ((tid >> 4) & 31) * 4;     // 4-pixel group

    const float* inb = inputs + (size_t)b * NC * HWP;
    f32x4 pa0 = 0.f, pa1 = 0.f, pa2 = 0.f, pa3 = 0.f;   // [4ch][4px]

    for (int tap0 = 0; tap0 < TT; tap0 += 21) {
        int ntap = (TT - tap0 < 21) ? (TT - tap0) : 21;
        int M = 3 * ntap;
        __syncthreads();   // prior GEMM2 reads of As/Bs complete
        // stage dw -> Bs (swizzled)
        {
            const float* bp = dw + (size_t)b * CF * HWP + p0;
            for (int i4 = tid; i4 < 64 * 32; i4 += 512) {
                int kk = i4 >> 5, f4 = (i4 & 31) * 4;
                *(float4*)&Bs[kk][SW(kk, f4)] = *(const float4*)(bp + (size_t)kk * HWP + f4);
            }
        }
        // stage pw^T -> As[kk][m]
        {
            int m = tid & 63;
            int kq = tid >> 6;   // 0..7
            if (m < M) {
                int i = m / 3, q = m - 3 * i;
                int r = tap0 + i;
                int srow = (q == 2) ? (2 * TT + r) : (2 * r + q);
                const float* ap = pw_w + (size_t)srow * CF;
#pragma unroll
                for (int i2 = 0; i2 < 2; ++i2) {
                    int k0 = kq * 8 + i2 * 4;
                    float4 v = *(const float4*)(ap + k0);
                    As[k0 + 0][m] = v.x; As[k0 + 1][m] = v.y;
                    As[k0 + 2][m] = v.z; As[k0 + 3][m] = v.w;
                }
            }
        }
        __syncthreads();
        // GEMM1: C[m][px], K=64, 4x4 microtile
        f32x4 c0 = 0.f, c1 = 0.f, c2 = 0.f, c3 = 0.f;
#pragma unroll 8
        for (int kk = 0; kk < 64; ++kk) {
            f32x4 a  = *(const f32x4*)&As[kk][tm];
            f32x4 bv = *(const f32x4*)&Bs[kk][SW(kk, tn)];
#pragma unroll
            for (int j = 0; j < 4; ++j) {
                c0[j] += a[0] * bv[j]; c1[j] += a[1] * bv[j];
                c2[j] += a[2] * bv[j]; c3[j] += a[3] * bv[j];
            }
        }
        __syncthreads();   // all GEMM1 reads of As/Bs done
        // park C+bias into Bs rows 0..M-1 (swizzled); stage dcn into dead As
        {
            f32x4 cs[4] = {c0, c1, c2, c3};
#pragma unroll
            for (int r2 = 0; r2 < 4; ++r2) {
                int m = tm + r2;
                if (m < M) {
                    int i = m / 3, q = m - 3 * i;
                    int r = tap0 + i;
                    float bi = pw_b[(q == 2) ? (2 * TT + r) : (2 * r + q)];
                    f32x4 v = cs[r2];
#pragma unroll
                    for (int j = 0; j < 4; ++j) v[j] += bi;
                    *(f32x4*)&Bs[m][SW(m, tn)] = v;
                }
            }
        }
        for (int i4 = tid; i4 < ntap * 16; i4 += 512) {
            int row = i4 >> 4, c4 = (i4 & 15) * 4;
            *(float4*)&As[row][c4] = *(const float4*)(dcn_wt + (size_t)(tap0 + row) * OO + c4);
        }
        __syncthreads();
        // sample in place in Bs (row 3i <- s), 4 threads per pixel
        {
            int px = tid & 127;
            int p = p0 + px;
            int h = p / WW, wq = p % WW;
            for (int i = tid >> 7; i < ntap; i += 4) {
                int r = tap0 + i;
                float oy = Bs[3 * i][SW(3 * i, px)];
                float ox = Bs[3 * i + 1][SW(3 * i + 1, px)];
                float mr = Bs[3 * i + 2][SW(3 * i + 2, px)];
                int c = r / K;
                int kk2 = r - c * K;
                int ky = kk2 / k, kx = kk2 - ky * k;
                const float* inc_ = inb + (size_t)c * HWP;
                float m = 1.f / (1.f + __expf(-mr));
                float py = oy + (float)(ky + h - pad);
                float px_ = ox + (float)(kx + wq - pad);
                float y0 = floorf(py), x0 = floorf(px_);
                float wyf = py - y0, wxf = px_ - x0;
                int iy0 = (int)y0, ix0 = (int)x0;
                bool y0v = (iy0 >= 0) && (iy0 < HH);
                bool y1v = (iy0 + 1 >= 0) && (iy0 + 1 < HH);
                bool x0v = (ix0 >= 0) && (ix0 < WW);
                bool x1v = (ix0 + 1 >= 0) && (ix0 + 1 < WW);
                int yc0 = min(max(iy0, 0), HH - 1), yc1 = min(max(iy0 + 1, 0), HH - 1);
                int xc0 = min(max(ix0, 0), WW - 1), xc1 = min(max(ix0 + 1, 0), WW - 1);
                float v00 = 0.f, v01 = 0.f, v10 = 0.f, v11 = 0.f;
                if (y0v) {
                    if (x0v) v00 = inc_[yc0 * WW + xc0];
                    if (x1v) v01 = inc_[yc0 * WW + xc1];
                }
                if (y1v) {
                    if (x0v) v10 = inc_[yc1 * WW + xc0];
                    if (x1v) v11 = inc_[yc1 * WW + xc1];
                }
                float s = (v00 * (1.f - wyf) * (1.f - wxf) + v01 * (1.f - wyf) * wxf +
                           v10 * wyf * (1.f - wxf) + v11 * wyf * wxf) * m;
                Bs[3 * i][SW(3 * i, px)] = s;   // sole owner of (i,px)
            }
        }
        __syncthreads();
        // GEMM2: acc[ch][px] += dcn[tap][ch] * s[tap][px]
        for (int kk = 0; kk < ntap; ++kk) {
            f32x4 a = *(const f32x4*)&As[kk][tm];
            f32x4 s = *(const f32x4*)&Bs[3 * kk][SW(3 * kk, tn)];
#pragma unroll
            for (int j = 0; j < 4; ++j) {
                pa0[j] += a[0] * s[j]; pa1[j] += a[1] * s[j];
                pa2[j] += a[2] * s[j]; pa3[j] += a[3] * s[j];
            }
        }
    }
    __syncthreads();
    // epilogue: bias+relu, repack into Bs (swizzled), coalesced store
    {
        f32x4 accs[4] = {pa0, pa1, pa2, pa3};
#pragma unroll
        for (int r2 = 0; r2 < 4; ++r2) {
            int ch = tm + r2;
            float bi = dcn_b[ch];
            f32x4 v = accs[r2];
#pragma unroll
            for (int j = 0; j < 4; ++j) {
                v[j] += bi;
                v[j] = v[j] > 0.f ? v[j] : 0.f;
            }
            *(f32x4*)&Bs[ch][SW(ch, tn)] = v;
        }
    }
    __syncthreads();
    {
        float* op = outbuf + (size_t)((b * 3 + t_slot) * OO) * HWP + p0;
        for (int i4 = tid; i4 < 64 * 32; i4 += 512) {
            int row = i4 >> 5, f4 = (i4 & 31) * 4;
            *(float4*)(op + (size_t)row * HWP + f4) = *(const float4*)&Bs[row][SW(row, f4)];
        }
    }
}

// ---------------- attention GEMM, KC=32 LDS chunks ------------------------
__global__ __launch_bounds__(256)
void attn_gemm_kernel(const float* __restrict__ outbuf, const float* __restrict__ attn_wt,
                      const float* __restrict__ attn_b, float* __restrict__ partial) {
    __shared__ float As[32][68];
    __shared__ float Bs[32][132];
    __shared__ float red[16][68];
    int nb0 = blockIdx.x * 128;
    int b = nb0 / HWP, p0 = nb0 % HWP;
    int tid = threadIdx.x;
    int tm = (tid & 15) * 4;
    int tn = (tid >> 4) * 8;

    f32x4 aA0 = 0.f, aA1 = 0.f, aB0 = 0.f, aB1 = 0.f;
    f32x4 aC0 = 0.f, aC1 = 0.f, aD0 = 0.f, aD1 = 0.f;
    for (int kc = 0; kc < 6; ++kc) {
        for (int i4 = tid; i4 < 32 * 16; i4 += 256) {
            int row = i4 >> 4, c4 = (i4 & 15) * 4;
            float4 v = *(const float4*)(attn_wt + (size_t)(kc * 32 + row) * OO + c4);
            As[row][c4] = v.x; As[row][c4 + 1] = v.y; As[row][c4 + 2] = v.z; As[row][c4 + 3] = v.w;
        }
        const float* bp = outbuf + ((size_t)(b * 192 + kc * 32)) * HWP + p0;
        for (int i4 = tid; i4 < 32 * 32; i4 += 256) {
            int row = i4 >> 5, f4 = (i4 & 31) * 4;
            float4 v = *(const float4*)(bp + (size_t)row * HWP + f4);
            *(float4*)&Bs[row][f4] = v;
        }
        __syncthreads();
#pragma unroll 4
        for (int kk = 0; kk < 32; ++kk) {
            f32x4 a  = *(const f32x4*)&As[kk][tm];
            f32x4 b0 = *(const f32x4*)&Bs[kk][tn];
            f32x4 b1 = *(const f32x4*)&Bs[kk][tn + 4];
#pragma unroll
            for (int j = 0; j < 4; ++j) {
                aA0[j] += a[0] * b0[j];  aA1[j] += a[0] * b1[j];
                aB0[j] += a[1] * b0[j];  aB1[j] += a[1] * b1[j];
                aC0[j] += a[2] * b0[j];  aC1[j] += a[2] * b1[j];
                aD0[j] += a[3] * b0[j];  aD1[j] += a[3] * b1[j];
            }
        }
        __syncthreads();
    }
    float bsum[4];
    {
        f32x4 accs[8] = {aA0, aA1, aB0, aB1, aC0, aC1, aD0, aD1};
#pragma unroll
        for (int row = 0; row < 4; ++row) {
            float bi = attn_b[tm + row];
            float s = 0.f;
#pragma unroll
            for (int j = 0; j < 4; ++j) {
                float v0 = accs[row * 2][j] + bi;
                float v1 = accs[row * 2 + 1][j] + bi;
                s += (v0 > 0.f ? v0 : 0.f) + (v1 > 0.f ? v1 : 0.f);
            }
            bsum[row] = s;
        }
    }
    int pg = tid >> 4;
#pragma unroll
    for (int row = 0; row < 4; ++row) red[pg][tm + row] = bsum[row];
    __syncthreads();
    if (tid < 64) {
        float s = 0.f;
#pragma unroll
        for (int g = 0; g < 16; ++g) s += red[g][tid];
        int lb = p0 / 128;
        partial[((size_t)(b * PBLK2 + lb)) * OO + tid] = s;
    }
}

// ---------------- attention finish ----------------
__global__ void attn_finish_kernel(const float* __restrict__ partial,
                                   const float* __restrict__ fc_w, const float* __restrict__ fc_b,
                                   const float* __restrict__ fcs_w0, const float* __restrict__ fcs_b0,
                                   const float* __restrict__ fcs_w1, const float* __restrict__ fcs_b1,
                                   const float* __restrict__ fcs_w2, const float* __restrict__ fcs_b2,
                                   float* __restrict__ atts) {
    int b = blockIdx.x;
    __shared__ float attm[OO];
    __shared__ float fcv[32];
    int tid = threadIdx.x;
    if (tid < OO) {
        float s = 0.f;
        for (int blk = 0; blk < PBLK2; ++blk)
            s += partial[((size_t)(b * PBLK2 + blk)) * OO + tid];
        attm[tid] = s / (float)HWP;
    }
    __syncthreads();
    if (tid < 32) {
        float s = fc_b[tid];
        for (int o = 0; o < OO; ++o) s += fc_w[tid * OO + o] * attm[o];
        fcv[tid] = s > 0.f ? s : 0.f;
    }
    __syncthreads();
    if (tid < OO) {
        {
            float s = fcs_b0[tid];
            for (int j = 0; j < 32; ++j) s += fcs_w0[tid * 32 + j] * fcv[j];
            atts[b * 192 + 0 * OO + tid] = s;
        }
        {
            float s = fcs_b1[tid];
            for (int j = 0; j < 32; ++j) s += fcs_w1[tid * 32 + j] * fcv[j];
            atts[b * 192 + 1 * OO + tid] = s;
        }
        {
            float s = fcs_b2[tid];
            for (int j = 0; j < 32; ++j) s += fcs_w2[tid * 32 + j] * fcv[j];
            atts[b * 192 + 2 * OO + tid] = s;
        }
    }
}

// ---------------- final GEMM, KC=32 LDS chunks ----------------------------
__global__ __launch_bounds__(256)
void final_gemm_kernel(const float* __restrict__ outbuf, const float* __restrict__ atts,
                       const float* __restrict__ conv_wt, const float* __restrict__ conv_b,
                       float* __restrict__ out) {
    __shared__ float As[32][68];
    __shared__ float Bs[32][132];
    int nb0 = blockIdx.x * 128;
    int b = nb0 / HWP, p0 = nb0 % HWP;
    int tid = threadIdx.x;
    int tm = (tid & 15) * 4;
    int tn = (tid >> 4) * 8;
    const float* at = atts + b * 192;

    f32x4 aA0 = 0.f, aA1 = 0.f, aB0 = 0.f, aB1 = 0.f;
    f32x4 aC0 = 0.f, aC1 = 0.f, aD0 = 0.f, aD1 = 0.f;
    for (int kc = 0; kc < 6; ++kc) {
        for (int i4 = tid; i4 < 32 * 16; i4 += 256) {
            int row = i4 >> 4, c4 = (i4 & 15) * 4;
            float4 v = *(const float4*)(conv_wt + (size_t)(kc * 32 + row) * OO + c4);
            As[row][c4] = v.x; As[row][c4 + 1] = v.y; As[row][c4 + 2] = v.z; As[row][c4 + 3] = v.w;
        }
        const float* bp = outbuf + ((size_t)(b * 192 + kc * 32)) * HWP + p0;
        for (int i4 = tid; i4 < 32 * 32; i4 += 256) {
            int row = i4 >> 5, f4 = (i4 & 31) * 4;
            float sc = at[kc * 32 + row];
            float4 v = *(const float4*)(bp + (size_t)row * HWP + f4);
            Bs[row][f4] = v.x * sc; Bs[row][f4 + 1] = v.y * sc;
            Bs[row][f4 + 2] = v.z * sc; Bs[row][f4 + 3] = v.w * sc;
        }
        __syncthreads();
#pragma unroll 4
        for (int kk = 0; kk < 32; ++kk) {
            f32x4 a  = *(const f32x4*)&As[kk][tm];
            f32x4 b0 = *(const f32x4*)&Bs[kk][tn];
            f32x4 b1 = *(const f32x4*)&Bs[kk][tn + 4];
#pragma unroll
            for (int j = 0; j < 4; ++j) {
                aA0[j] += a[0] * b0[j];  aA1[j] += a[0] * b1[j];
                aB0[j] += a[1] * b0[j];  aB1[j] += a[1] * b1[j];
                aC0[j] += a[2] * b0[j];  aC1[j] += a[2] * b1[j];
                aD0[j] += a[3] * b0[j];  aD1[j] += a[3] * b1[j];
            }
        }
        __syncthreads();
    }
    f32x4 accs[8] = {aA0, aA1, aB0, aB1, aC0, aC1, aD0, aD1};
#pragma unroll
    for (int row = 0; row < 4; ++row) {
        int ch = tm + row;
        float bi = conv_b[ch];
        float* ptr = out + ((size_t)(b * OO + ch)) * HWP + p0 + tn;
        f32x4 lo = accs[row * 2], hi = accs[row * 2 + 1];
#pragma unroll
        for (int j = 0; j < 4; ++j) {
            lo[j] += bi; hi[j] += bi;
            lo[j] = lo[j] > 0.f ? lo[j] : 0.f;
            hi[j] = hi[j] > 0.f ? hi[j] : 0.f;
        }
        *(f32x4*)ptr = lo;
        *(f32x4*)(ptr + 4) = hi;
    }
}

extern "C" void kernel_launch(void* const* d_in, const int* in_sizes, int n_in,
                              void* d_out, int out_size, void* d_ws, size_t ws_size,
                              hipStream_t stream) {
    const float* fea    = (const float*)d_in[0];
    const float* inputs = (const float*)d_in[1];
    const float* dw_w[3]  = {(const float*)d_in[2],  (const float*)d_in[8],  (const float*)d_in[14]};
    const float* dw_b[3]  = {(const float*)d_in[3],  (const float*)d_in[9],  (const float*)d_in[15]};
    const float* pw_w[3]  = {(const float*)d_in[4],  (const float*)d_in[10], (const float*)d_in[16]};
    const float* pw_b[3]  = {(const float*)d_in[5],  (const float*)d_in[11], (const float*)d_in[17]};
    const float* dcn_w[3] = {(const float*)d_in[6],  (const float*)d_in[12], (const float*)d_in[18]};
    const float* dcn_b[3] = {(const float*)d_in[7],  (const float*)d_in[13], (const float*)d_in[19]};
    const float* attn_w = (const float*)d_in[20];
    const float* attn_b = (const float*)d_in[21];
    const float* fc_w   = (const float*)d_in[22];
    const float* fc_b   = (const float*)d_in[23];
    const float* fcs_w[3] = {(const float*)d_in[24], (const float*)d_in[26], (const float*)d_in[28]};
    const float* fcs_b[3] = {(const float*)d_in[25], (const float*)d_in[27], (const float*)d_in[29]};
    const float* conv_w = (const float*)d_in[30];
    const float* conv_b = (const float*)d_in[31];
    float* out = (float*)d_out;

    const size_t F_OUTBUF = (size_t)BB * 3 * OO * HWP;   // 28,311,552
    float* W = (float*)d_ws;
    float* outbuf = W;            W += F_OUTBUF;
    float* partial = W;           W += 73728;    // BB*PBLK2*64
    float* atts = W;              W += 768;
    float* dcn_wt0 = W;           W += 512;
    float* dcn_wt1 = W;           W += 4096;
    float* dcn_wt2 = W;           W += 11264;
    float* attn_wt = W;           W += 12288;
    float* conv_wt = W;           W += 12288;
    float* pw_wf = W;             W += 1344;     // folded k1 pw weights (21x64)
    float* pw_bf = W;             W += 32;       // folded k1 bias (21)
    float* dwscr = out;           // d_out as dw-plane scratch; final_gemm rewrites d_out

    transpose_kernel<<<(192 * 64 + 255) / 256, 256, 0, stream>>>(attn_w, attn_wt, 64, 192);
    transpose_kernel<<<(192 * 64 + 255) / 256, 256, 0, stream>>>(conv_w, conv_wt, 64, 192);
    transpose_kernel<<<(7 * 64 + 255) / 256, 256, 0, stream>>>(dcn_w[0], dcn_wt0, 64, 7);
    transpose_kernel<<<(63 * 64 + 255) / 256, 256, 0, stream>>>(dcn_w[1], dcn_wt1, 64, 63);
    transpose_kernel<<<(175 * 64 + 255) / 256, 256, 0, stream>>>(dcn_w[2], dcn_wt2, 64, 175);
    k1_fold_kernel<<<(21 * 64 + 255) / 256, 256, 0, stream>>>(pw_w[0], pw_b[0],
                                                              dw_w[0], dw_b[0], pw_wf, pw_bf);

    const int dwv_grid = (BB * CF * HH * 48) / 256;   // 9216
    const int fuse_grid = NTOT / 128;                 // 1152

    // ---- k=5 branch ----
    dwv_kernel<5><<<dwv_grid, 256, 0, stream>>>(fea, dw_w[2], dw_b[2], dwscr);
    branch_fused_kernel<5><<<fuse_grid, 512, 0, stream>>>(
        pw_w[2], pw_b[2], dwscr, inputs, dcn_wt2, dcn_b[2], outbuf, 2);
    // ---- k=3 branch ----
    dwv_kernel<3><<<dwv_grid, 256, 0, stream>>>(fea, dw_w[1], dw_b[1], dwscr);
    branch_fused_kernel<3><<<fuse_grid, 512, 0, stream>>>(
        pw_w[1], pw_b[1], dwscr, inputs, dcn_wt1, dcn_b[1], outbuf, 1);
    // ---- k=1 branch: folded weights, B operand = fea directly ----
    branch_fused_kernel<1><<<fuse_grid, 512, 0, stream>>>(
        pw_wf, pw_bf, fea, inputs, dcn_wt0, dcn_b[0], outbuf, 0);

    // ---- attention + final (tiled GEMMs, KC=32) ----
    attn_gemm_kernel<<<NTOT / 128, 256, 0, stream>>>(outbuf, attn_wt, attn_b, partial);
    attn_finish_kernel<<<BB, 64, 0, stream>>>(partial, fc_w, fc_b,
                                              fcs_w[0], fcs_b[0], fcs_w[1], fcs_b[1],
                                              fcs_w[2], fcs_b[2], atts);
    final_gemm_kernel<<<NTOT / 128, 256, 0, stream>>>(outbuf, atts, conv_wt, conv_b, out);
}

// Round 18
// 617.275 us; speedup vs baseline: 1.1107x; 1.1107x over previous
//
#include <hip/hip_runtime.h>
#include <math.h>

#define HH 192
#define WW 192
#define HWP (192*192)
#define BB 4
#define CF 64
#define NC 7
#define OO 64
#define NTOT (BB*HWP)          // 147456
#define PBLK2 (HWP/128)        // 288

// bank swizzle for Cs only (park/sample/epilogue paths): XOR col bits 2-4
// with row bits 2-4; float4-alignment preserving; bijective per row.
#define SW(r, c) ((c) ^ ((((r) >> 2) & 7) << 2))

typedef float f32x4 __attribute__((ext_vector_type(4)));

// ---------------- vectorized depthwise conv: 4 outputs/thread -------------
template<int k>
__global__ __launch_bounds__(256)
void dwv_kernel(const float* __restrict__ fea, const float* __restrict__ w,
                const float* __restrict__ bias, float* __restrict__ out) {
    constexpr int pad = k / 2;
    int idx = blockIdx.x * 256 + threadIdx.x;      // over B*CF*HH*48
    int xq = idx % 48;
    int x0 = xq * 4;
    int hpos = (idx / 48) % HH;
    int plane = idx / (48 * HH);
    int c = plane % CF;
    const float* f = fea + (size_t)plane * HWP;

    float wk[k * k];
#pragma unroll
    for (int i = 0; i < k * k; ++i) wk[i] = w[c * k * k + i];

    float acc0 = 0.f, acc1 = 0.f, acc2 = 0.f, acc3 = 0.f;
#pragma unroll
    for (int dy = 0; dy < k; ++dy) {
        int y = hpos + dy - pad;
        if (y < 0 || y >= HH) continue;
        const float* row = f + y * WW;
        float4 q0 = (x0 >= 4) ? *(const float4*)(row + x0 - 4) : make_float4(0.f, 0.f, 0.f, 0.f);
        float4 q1 = *(const float4*)(row + x0);
        float4 q2 = (x0 + 4 < WW) ? *(const float4*)(row + x0 + 4) : make_float4(0.f, 0.f, 0.f, 0.f);
        float wnd[8] = {q0.z, q0.w, q1.x, q1.y, q1.z, q1.w, q2.x, q2.y};
#pragma unroll
        for (int dx = 0; dx < k; ++dx) {
            float wt = wk[dy * k + dx];
            acc0 += wnd[0 + dx + 2 - pad] * wt;
            acc1 += wnd[1 + dx + 2 - pad] * wt;
            acc2 += wnd[2 + dx + 2 - pad] * wt;
            acc3 += wnd[3 + dx + 2 - pad] * wt;
        }
    }
    float b = bias[c];
    float4 o = make_float4(acc0 + b, acc1 + b, acc2 + b, acc3 + b);
    *(float4*)(out + (size_t)plane * HWP + hpos * WW + x0) = o;
}

// ---------------- generic small transpose ----------------
__global__ void transpose_kernel(const float* __restrict__ in, float* __restrict__ out,
                                 int rows, int cols) {
    int idx = blockIdx.x * 256 + threadIdx.x;
    if (idx >= rows * cols) return;
    int r = idx / cols, c = idx % cols;
    out[c * rows + r] = in[idx];
}

// ---------------- k1 weight fold: pw_w' = pw_w*diag(w0), b' = pw_b+pw_w@b0
__global__ void k1_fold_kernel(const float* __restrict__ pw_w, const float* __restrict__ pw_b,
                               const float* __restrict__ dw_w0, const float* __restrict__ dw_b0,
                               float* __restrict__ pw_wf, float* __restrict__ pw_bf) {
    int i = blockIdx.x * 256 + threadIdx.x;
    if (i < 21 * 64) pw_wf[i] = pw_w[i] * dw_w0[i & 63];
    if (i < 21) {
        float s = pw_b[i];
        for (int c = 0; c < 64; ++c) s += pw_w[i * 64 + c] * dw_b0[c];
        pw_bf[i] = s;
    }
}

// ---------------- fully fused branch kernel (round-14 structure) ----------
// Round-17: R14 config (256t, N=64, As/Bs/Cs) restored — the best measured
// (613us total). Swizzle applied ONLY on Cs park/sample/epilogue accesses
// (the 8-way-conflict paths); GEMM1 As/Bs paths untouched (no inner-loop
// address arithmetic — the R16 mistake).
template<int k>
__global__ __launch_bounds__(256)
void branch_fused_kernel(const float* __restrict__ pw_w, const float* __restrict__ pw_b,
                         const float* __restrict__ dw, const float* __restrict__ inputs,
                         const float* __restrict__ dcn_wt, const float* __restrict__ dcn_b,
                         float* __restrict__ outbuf, int t_slot) {
    constexpr int K = k * k;
    constexpr int TT = NC * K;
    constexpr int pad = k / 2;
    __shared__ float As[64][68];
    __shared__ float Bs[64][68];
    __shared__ float Cs[64][68];
    int nb0 = blockIdx.x * 64;
    int b = nb0 / HWP, p0 = nb0 % HWP;
    int tid = threadIdx.x;
    int tm = (tid & 15) * 4;
    int tn = (tid >> 4) * 4;

    // stage dw tile Bs[kk][px] once
    {
        const float* bp = dw + (size_t)b * CF * HWP + p0;
        for (int i4 = tid; i4 < 64 * 16; i4 += 256) {
            int kk = i4 >> 4, f4 = (i4 & 15) * 4;
            float4 v = *(const float4*)(bp + (size_t)kk * HWP + f4);
            *(float4*)&Bs[kk][f4] = v;
        }
    }

    f32x4 acc0 = 0.f, acc1 = 0.f, acc2 = 0.f, acc3 = 0.f;   // [4ch][4px]
    const float* inb = inputs + (size_t)b * NC * HWP;

    for (int tap0 = 0; tap0 < TT; tap0 += 21) {
        int ntap = (TT - tap0 < 21) ? (TT - tap0) : 21;
        int M = 3 * ntap;
        __syncthreads();   // prior GEMM2 done (As/Cs reads); 1st iter: Bs staged
        // stage A: As[kk][m] = pw_w[srow(m)][kk]
        {
            int m = tid & 63;
            int kq = tid >> 6;   // 0..3
            if (m < M) {
                int i = m / 3, q = m - 3 * i;
                int r = tap0 + i;
                int srow = (q == 2) ? (2 * TT + r) : (2 * r + q);
                const float* ap = pw_w + (size_t)srow * CF;
#pragma unroll
                for (int i2 = 0; i2 < 4; ++i2) {
                    int k0 = (kq * 4 + i2) * 4;
                    float4 v = *(const float4*)(ap + k0);
                    As[k0 + 0][m] = v.x; As[k0 + 1][m] = v.y;
                    As[k0 + 2][m] = v.z; As[k0 + 3][m] = v.w;
                }
            }
        }
        __syncthreads();
        // GEMM1: C[m][px], K=64 (unswizzled As/Bs — broadcast/2-way free)
        f32x4 c0 = 0.f, c1 = 0.f, c2 = 0.f, c3 = 0.f;
#pragma unroll 8
        for (int kk = 0; kk < 64; ++kk) {
            f32x4 a = *(const f32x4*)&As[kk][tm];
            f32x4 bv = *(const f32x4*)&Bs[kk][tn];
#pragma unroll
            for (int j = 0; j < 4; ++j) {
                c0[j] += a[0] * bv[j]; c1[j] += a[1] * bv[j];
                c2[j] += a[2] * bv[j]; c3[j] += a[3] * bv[j];
            }
        }
        // park C + bias into Cs (swizzled cols — kills the 8-way m-stride-4
        // write conflict); Cs dead since loop-top sync
        {
            f32x4 cs[4] = {c0, c1, c2, c3};
#pragma unroll
            for (int r2 = 0; r2 < 4; ++r2) {
                int m = tm + r2;
                if (m < M) {
                    int i = m / 3, q = m - 3 * i;
                    int r = tap0 + i;
                    float bi = pw_b[(q == 2) ? (2 * TT + r) : (2 * r + q)];
                    f32x4 v = cs[r2];
#pragma unroll
                    for (int j = 0; j < 4; ++j) v[j] += bi;
                    *(f32x4*)&Cs[m][SW(m, tn)] = v;
                }
            }
        }
        __syncthreads();
        // (a) stage dcn rows into As (dead after GEMM1); (b) sample in place
        for (int i4 = tid; i4 < ntap * 16; i4 += 256) {
            int row = i4 >> 4, c4 = (i4 & 15) * 4;
            float4 v = *(const float4*)(dcn_wt + (size_t)(tap0 + row) * OO + c4);
            *(float4*)&As[row][c4] = v;
        }
        {
            int px = tid & 63;
            int p = p0 + px;
            int h = p / WW, wq = p % WW;
            for (int i = tid >> 6; i < ntap; i += 4) {
                int r = tap0 + i;
                float oy = Cs[3 * i][SW(3 * i, px)];
                float ox = Cs[3 * i + 1][SW(3 * i + 1, px)];
                float mr = Cs[3 * i + 2][SW(3 * i + 2, px)];
                int c = r / K;
                int kk2 = r - c * K;
                int ky = kk2 / k, kx = kk2 - ky * k;
                const float* inc_ = inb + (size_t)c * HWP;
                float m = 1.f / (1.f + __expf(-mr));
                float py = oy + (float)(ky + h - pad);
                float px_ = ox + (float)(kx + wq - pad);
                float y0 = floorf(py), x0 = floorf(px_);
                float wyf = py - y0, wxf = px_ - x0;
                int iy0 = (int)y0, ix0 = (int)x0;
                bool y0v = (iy0 >= 0) && (iy0 < HH);
                bool y1v = (iy0 + 1 >= 0) && (iy0 + 1 < HH);
                bool x0v = (ix0 >= 0) && (ix0 < WW);
                bool x1v = (ix0 + 1 >= 0) && (ix0 + 1 < WW);
                int yc0 = min(max(iy0, 0), HH - 1), yc1 = min(max(iy0 + 1, 0), HH - 1);
                int xc0 = min(max(ix0, 0), WW - 1), xc1 = min(max(ix0 + 1, 0), WW - 1);
                float v00 = 0.f, v01 = 0.f, v10 = 0.f, v11 = 0.f;
                if (y0v) {
                    if (x0v) v00 = inc_[yc0 * WW + xc0];
                    if (x1v) v01 = inc_[yc0 * WW + xc1];
                }
                if (y1v) {
                    if (x0v) v10 = inc_[yc1 * WW + xc0];
                    if (x1v) v11 = inc_[yc1 * WW + xc1];
                }
                float s = (v00 * (1.f - wyf) * (1.f - wxf) + v01 * (1.f - wyf) * wxf +
                           v10 * wyf * (1.f - wxf) + v11 * wyf * wxf) * m;
                Cs[3 * i][SW(3 * i, px)] = s;   // in-place: sole owner of (i,px)
            }
        }
        __syncthreads();
        // GEMM2: acc[ch][px] += dcn[tap][ch] * s[tap][px]
        // (Cs read: row fixed per kk, 4 distinct swizzled cols -> broadcast, free)
        for (int kk = 0; kk < ntap; ++kk) {
            f32x4 a = *(const f32x4*)&As[kk][tm];
            f32x4 s = *(const f32x4*)&Cs[3 * kk][SW(3 * kk, tn)];
#pragma unroll
            for (int j = 0; j < 4; ++j) {
                acc0[j] += a[0] * s[j]; acc1[j] += a[1] * s[j];
                acc2[j] += a[2] * s[j]; acc3[j] += a[3] * s[j];
            }
        }
    }
    __syncthreads();
    // epilogue: bias+relu, repack into Cs (swizzled), coalesced store
    {
        f32x4 accs[4] = {acc0, acc1, acc2, acc3};
#pragma unroll
        for (int r2 = 0; r2 < 4; ++r2) {
            int ch = tm + r2;
            float bi = dcn_b[ch];
            f32x4 v = accs[r2];
#pragma unroll
            for (int j = 0; j < 4; ++j) {
                v[j] += bi;
                v[j] = v[j] > 0.f ? v[j] : 0.f;
            }
            *(f32x4*)&Cs[ch][SW(ch, tn)] = v;
        }
    }
    __syncthreads();
    {
        float* op = outbuf + (size_t)((b * 3 + t_slot) * OO) * HWP + p0;
        for (int i4 = tid; i4 < 64 * 16; i4 += 256) {
            int row = i4 >> 4, f4 = (i4 & 15) * 4;
            *(float4*)(op + (size_t)row * HWP + f4) = *(const float4*)&Cs[row][SW(row, f4)];
        }
    }
}

// ---------------- attention GEMM, KC=32 LDS chunks ------------------------
__global__ __launch_bounds__(256)
void attn_gemm_kernel(const float* __restrict__ outbuf, const float* __restrict__ attn_wt,
                      const float* __restrict__ attn_b, float* __restrict__ partial) {
    __shared__ float As[32][68];
    __shared__ float Bs[32][132];
    __shared__ float red[16][68];
    int nb0 = blockIdx.x * 128;
    int b = nb0 / HWP, p0 = nb0 % HWP;
    int tid = threadIdx.x;
    int tm = (tid & 15) * 4;
    int tn = (tid >> 4) * 8;

    f32x4 aA0 = 0.f, aA1 = 0.f, aB0 = 0.f, aB1 = 0.f;
    f32x4 aC0 = 0.f, aC1 = 0.f, aD0 = 0.f, aD1 = 0.f;
    for (int kc = 0; kc < 6; ++kc) {
        for (int i4 = tid; i4 < 32 * 16; i4 += 256) {
            int row = i4 >> 4, c4 = (i4 & 15) * 4;
            float4 v = *(const float4*)(attn_wt + (size_t)(kc * 32 + row) * OO + c4);
            As[row][c4] = v.x; As[row][c4 + 1] = v.y; As[row][c4 + 2] = v.z; As[row][c4 + 3] = v.w;
        }
        const float* bp = outbuf + ((size_t)(b * 192 + kc * 32)) * HWP + p0;
        for (int i4 = tid; i4 < 32 * 32; i4 += 256) {
            int row = i4 >> 5, f4 = (i4 & 31) * 4;
            float4 v = *(const float4*)(bp + (size_t)row * HWP + f4);
            *(float4*)&Bs[row][f4] = v;
        }
        __syncthreads();
#pragma unroll 4
        for (int kk = 0; kk < 32; ++kk) {
            f32x4 a  = *(const f32x4*)&As[kk][tm];
            f32x4 b0 = *(const f32x4*)&Bs[kk][tn];
            f32x4 b1 = *(const f32x4*)&Bs[kk][tn + 4];
#pragma unroll
            for (int j = 0; j < 4; ++j) {
                aA0[j] += a[0] * b0[j];  aA1[j] += a[0] * b1[j];
                aB0[j] += a[1] * b0[j];  aB1[j] += a[1] * b1[j];
                aC0[j] += a[2] * b0[j];  aC1[j] += a[2] * b1[j];
                aD0[j] += a[3] * b0[j];  aD1[j] += a[3] * b1[j];
            }
        }
        __syncthreads();
    }
    float bsum[4];
    {
        f32x4 accs[8] = {aA0, aA1, aB0, aB1, aC0, aC1, aD0, aD1};
#pragma unroll
        for (int row = 0; row < 4; ++row) {
            float bi = attn_b[tm + row];
            float s = 0.f;
#pragma unroll
            for (int j = 0; j < 4; ++j) {
                float v0 = accs[row * 2][j] + bi;
                float v1 = accs[row * 2 + 1][j] + bi;
                s += (v0 > 0.f ? v0 : 0.f) + (v1 > 0.f ? v1 : 0.f);
            }
            bsum[row] = s;
        }
    }
    int pg = tid >> 4;
#pragma unroll
    for (int row = 0; row < 4; ++row) red[pg][tm + row] = bsum[row];
    __syncthreads();
    if (tid < 64) {
        float s = 0.f;
#pragma unroll
        for (int g = 0; g < 16; ++g) s += red[g][tid];
        int lb = p0 / 128;
        partial[((size_t)(b * PBLK2 + lb)) * OO + tid] = s;
    }
}

// ---------------- attention finish ----------------
__global__ void attn_finish_kernel(const float* __restrict__ partial,
                                   const float* __restrict__ fc_w, const float* __restrict__ fc_b,
                                   const float* __restrict__ fcs_w0, const float* __restrict__ fcs_b0,
                                   const float* __restrict__ fcs_w1, const float* __restrict__ fcs_b1,
                                   const float* __restrict__ fcs_w2, const float* __restrict__ fcs_b2,
                                   float* __restrict__ atts) {
    int b = blockIdx.x;
    __shared__ float attm[OO];
    __shared__ float fcv[32];
    int tid = threadIdx.x;
    if (tid < OO) {
        float s = 0.f;
        for (int blk = 0; blk < PBLK2; ++blk)
            s += partial[((size_t)(b * PBLK2 + blk)) * OO + tid];
        attm[tid] = s / (float)HWP;
    }
    __syncthreads();
    if (tid < 32) {
        float s = fc_b[tid];
        for (int o = 0; o < OO; ++o) s += fc_w[tid * OO + o] * attm[o];
        fcv[tid] = s > 0.f ? s : 0.f;
    }
    __syncthreads();
    if (tid < OO) {
        {
            float s = fcs_b0[tid];
            for (int j = 0; j < 32; ++j) s += fcs_w0[tid * 32 + j] * fcv[j];
            atts[b * 192 + 0 * OO + tid] = s;
        }
        {
            float s = fcs_b1[tid];
            for (int j = 0; j < 32; ++j) s += fcs_w1[tid * 32 + j] * fcv[j];
            atts[b * 192 + 1 * OO + tid] = s;
        }
        {
            float s = fcs_b2[tid];
            for (int j = 0; j < 32; ++j) s += fcs_w2[tid * 32 + j] * fcv[j];
            atts[b * 192 + 2 * OO + tid] = s;
        }
    }
}

// ---------------- final GEMM, KC=32 LDS chunks ----------------------------
__global__ __launch_bounds__(256)
void final_gemm_kernel(const float* __restrict__ outbuf, const float* __restrict__ atts,
                       const float* __restrict__ conv_wt, const float* __restrict__ conv_b,
                       float* __restrict__ out) {
    __shared__ float As[32][68];
    __shared__ float Bs[32][132];
    int nb0 = blockIdx.x * 128;
    int b = nb0 / HWP, p0 = nb0 % HWP;
    int tid = threadIdx.x;
    int tm = (tid & 15) * 4;
    int tn = (tid >> 4) * 8;
    const float* at = atts + b * 192;

    f32x4 aA0 = 0.f, aA1 = 0.f, aB0 = 0.f, aB1 = 0.f;
    f32x4 aC0 = 0.f, aC1 = 0.f, aD0 = 0.f, aD1 = 0.f;
    for (int kc = 0; kc < 6; ++kc) {
        for (int i4 = tid; i4 < 32 * 16; i4 += 256) {
            int row = i4 >> 4, c4 = (i4 & 15) * 4;
            float4 v = *(const float4*)(conv_wt + (size_t)(kc * 32 + row) * OO + c4);
            As[row][c4] = v.x; As[row][c4 + 1] = v.y; As[row][c4 + 2] = v.z; As[row][c4 + 3] = v.w;
        }
        const float* bp = outbuf + ((size_t)(b * 192 + kc * 32)) * HWP + p0;
        for (int i4 = tid; i4 < 32 * 32; i4 += 256) {
            int row = i4 >> 5, f4 = (i4 & 31) * 4;
            float sc = at[kc * 32 + row];
            float4 v = *(const float4*)(bp + (size_t)row * HWP + f4);
            Bs[row][f4] = v.x * sc; Bs[row][f4 + 1] = v.y * sc;
            Bs[row][f4 + 2] = v.z * sc; Bs[row][f4 + 3] = v.w * sc;
        }
        __syncthreads();
#pragma unroll 4
        for (int kk = 0; kk < 32; ++kk) {
            f32x4 a  = *(const f32x4*)&As[kk][tm];
            f32x4 b0 = *(const f32x4*)&Bs[kk][tn];
            f32x4 b1 = *(const f32x4*)&Bs[kk][tn + 4];
#pragma unroll
            for (int j = 0; j < 4; ++j) {
                aA0[j] += a[0] * b0[j];  aA1[j] += a[0] * b1[j];
                aB0[j] += a[1] * b0[j];  aB1[j] += a[1] * b1[j];
                aC0[j] += a[2] * b0[j];  aC1[j] += a[2] * b1[j];
                aD0[j] += a[3] * b0[j];  aD1[j] += a[3] * b1[j];
            }
        }
        __syncthreads();
    }
    f32x4 accs[8] = {aA0, aA1, aB0, aB1, aC0, aC1, aD0, aD1};
#pragma unroll
    for (int row = 0; row < 4; ++row) {
        int ch = tm + row;
        float bi = conv_b[ch];
        float* ptr = out + ((size_t)(b * OO + ch)) * HWP + p0 + tn;
        f32x4 lo = accs[row * 2], hi = accs[row * 2 + 1];
#pragma unroll
        for (int j = 0; j < 4; ++j) {
            lo[j] += bi; hi[j] += bi;
            lo[j] = lo[j] > 0.f ? lo[j] : 0.f;
            hi[j] = hi[j] > 0.f ? hi[j] : 0.f;
        }
        *(f32x4*)ptr = lo;
        *(f32x4*)(ptr + 4) = hi;
    }
}

extern "C" void kernel_launch(void* const* d_in, const int* in_sizes, int n_in,
                              void* d_out, int out_size, void* d_ws, size_t ws_size,
                              hipStream_t stream) {
    const float* fea    = (const float*)d_in[0];
    const float* inputs = (const float*)d_in[1];
    const float* dw_w[3]  = {(const float*)d_in[2],  (const float*)d_in[8],  (const float*)d_in[14]};
    const float* dw_b[3]  = {(const float*)d_in[3],  (const float*)d_in[9],  (const float*)d_in[15]};
    const float* pw_w[3]  = {(const float*)d_in[4],  (const float*)d_in[10], (const float*)d_in[16]};
    const float* pw_b[3]  = {(const float*)d_in[5],  (const float*)d_in[11], (const float*)d_in[17]};
    const float* dcn_w[3] = {(const float*)d_in[6],  (const float*)d_in[12], (const float*)d_in[18]};
    const float* dcn_b[3] = {(const float*)d_in[7],  (const float*)d_in[13], (const float*)d_in[19]};
    const float* attn_w = (const float*)d_in[20];
    const float* attn_b = (const float*)d_in[21];
    const float* fc_w   = (const float*)d_in[22];
    const float* fc_b   = (const float*)d_in[23];
    const float* fcs_w[3] = {(const float*)d_in[24], (const float*)d_in[26], (const float*)d_in[28]};
    const float* fcs_b[3] = {(const float*)d_in[25], (const float*)d_in[27], (const float*)d_in[29]};
    const float* conv_w = (const float*)d_in[30];
    const float* conv_b = (const float*)d_in[31];
    float* out = (float*)d_out;

    const size_t F_OUTBUF = (size_t)BB * 3 * OO * HWP;   // 28,311,552
    float* W = (float*)d_ws;
    float* outbuf = W;            W += F_OUTBUF;
    float* partial = W;           W += 73728;    // BB*PBLK2*64
    float* atts = W;              W += 768;
    float* dcn_wt0 = W;           W += 512;
    float* dcn_wt1 = W;           W += 4096;
    float* dcn_wt2 = W;           W += 11264;
    float* attn_wt = W;           W += 12288;
    float* conv_wt = W;           W += 12288;
    float* pw_wf = W;             W += 1344;     // folded k1 pw weights (21x64)
    float* pw_bf = W;             W += 32;       // folded k1 bias (21)
    float* dwscr = out;           // d_out as dw-plane scratch; final_gemm rewrites d_out

    transpose_kernel<<<(192 * 64 + 255) / 256, 256, 0, stream>>>(attn_w, attn_wt, 64, 192);
    transpose_kernel<<<(192 * 64 + 255) / 256, 256, 0, stream>>>(conv_w, conv_wt, 64, 192);
    transpose_kernel<<<(7 * 64 + 255) / 256, 256, 0, stream>>>(dcn_w[0], dcn_wt0, 64, 7);
    transpose_kernel<<<(63 * 64 + 255) / 256, 256, 0, stream>>>(dcn_w[1], dcn_wt1, 64, 63);
    transpose_kernel<<<(175 * 64 + 255) / 256, 256, 0, stream>>>(dcn_w[2], dcn_wt2, 64, 175);
    k1_fold_kernel<<<(21 * 64 + 255) / 256, 256, 0, stream>>>(pw_w[0], pw_b[0],
                                                              dw_w[0], dw_b[0], pw_wf, pw_bf);

    const int dwv_grid = (BB * CF * HH * 48) / 256;   // 9216
    const int fuse_grid = NTOT / 64;                  // 2304

    // ---- k=5 branch ----
    dwv_kernel<5><<<dwv_grid, 256, 0, stream>>>(fea, dw_w[2], dw_b[2], dwscr);
    branch_fused_kernel<5><<<fuse_grid, 256, 0, stream>>>(
        pw_w[2], pw_b[2], dwscr, inputs, dcn_wt2, dcn_b[2], outbuf, 2);
    // ---- k=3 branch ----
    dwv_kernel<3><<<dwv_grid, 256, 0, stream>>>(fea, dw_w[1], dw_b[1], dwscr);
    branch_fused_kernel<3><<<fuse_grid, 256, 0, stream>>>(
        pw_w[1], pw_b[1], dwscr, inputs, dcn_wt1, dcn_b[1], outbuf, 1);
    // ---- k=1 branch: folded weights, B operand = fea directly ----
    branch_fused_kernel<1><<<fuse_grid, 256, 0, stream>>>(
        pw_wf, pw_bf, fea, inputs, dcn_wt0, dcn_b[0], outbuf, 0);

    // ---- attention + final (tiled GEMMs, KC=32) ----
    attn_gemm_kernel<<<NTOT / 128, 256, 0, stream>>>(outbuf, attn_wt, attn_b, partial);
    attn_finish_kernel<<<BB, 64, 0, stream>>>(partial, fc_w, fc_b,
                                              fcs_w[0], fcs_b[0], fcs_w[1], fcs_b[1],
                                              fcs_w[2], fcs_b[2], atts);
    final_gemm_kernel<<<NTOT / 128, 256, 0, stream>>>(outbuf, atts, conv_wt, conv_b, out);
}

// Round 19
// 602.393 us; speedup vs baseline: 1.1382x; 1.0247x over previous
//
#include <hip/hip_runtime.h>
#include <math.h>

#define HH 192
#define WW 192
#define HWP (192*192)
#define BB 4
#define CF 64
#define NC 7
#define OO 64
#define NTOT (BB*HWP)          // 147456
#define PBLK2 (HWP/128)        // 288

typedef float f32x4 __attribute__((ext_vector_type(4)));

// ---------------- vectorized depthwise conv: 4 outputs/thread -------------
template<int k>
__global__ __launch_bounds__(256)
void dwv_kernel(const float* __restrict__ fea, const float* __restrict__ w,
                const float* __restrict__ bias, float* __restrict__ out) {
    constexpr int pad = k / 2;
    int idx = blockIdx.x * 256 + threadIdx.x;      // over B*CF*HH*48
    int xq = idx % 48;
    int x0 = xq * 4;
    int hpos = (idx / 48) % HH;
    int plane = idx / (48 * HH);
    int c = plane % CF;
    const float* f = fea + (size_t)plane * HWP;

    float wk[k * k];
#pragma unroll
    for (int i = 0; i < k * k; ++i) wk[i] = w[c * k * k + i];

    float acc0 = 0.f, acc1 = 0.f, acc2 = 0.f, acc3 = 0.f;
#pragma unroll
    for (int dy = 0; dy < k; ++dy) {
        int y = hpos + dy - pad;
        if (y < 0 || y >= HH) continue;
        const float* row = f + y * WW;
        float4 q0 = (x0 >= 4) ? *(const float4*)(row + x0 - 4) : make_float4(0.f, 0.f, 0.f, 0.f);
        float4 q1 = *(const float4*)(row + x0);
        float4 q2 = (x0 + 4 < WW) ? *(const float4*)(row + x0 + 4) : make_float4(0.f, 0.f, 0.f, 0.f);
        float wnd[8] = {q0.z, q0.w, q1.x, q1.y, q1.z, q1.w, q2.x, q2.y};
#pragma unroll
        for (int dx = 0; dx < k; ++dx) {
            float wt = wk[dy * k + dx];
            acc0 += wnd[0 + dx + 2 - pad] * wt;
            acc1 += wnd[1 + dx + 2 - pad] * wt;
            acc2 += wnd[2 + dx + 2 - pad] * wt;
            acc3 += wnd[3 + dx + 2 - pad] * wt;
        }
    }
    float b = bias[c];
    float4 o = make_float4(acc0 + b, acc1 + b, acc2 + b, acc3 + b);
    *(float4*)(out + (size_t)plane * HWP + hpos * WW + x0) = o;
}

// ---------------- generic small transpose ----------------
__global__ void transpose_kernel(const float* __restrict__ in, float* __restrict__ out,
                                 int rows, int cols) {
    int idx = blockIdx.x * 256 + threadIdx.x;
    if (idx >= rows * cols) return;
    int r = idx / cols, c = idx % cols;
    out[c * rows + r] = in[idx];
}

// ---------------- k1 weight fold: pw_w' = pw_w*diag(w0), b' = pw_b+pw_w@b0
__global__ void k1_fold_kernel(const float* __restrict__ pw_w, const float* __restrict__ pw_b,
                               const float* __restrict__ dw_w0, const float* __restrict__ dw_b0,
                               float* __restrict__ pw_wf, float* __restrict__ pw_bf) {
    int i = blockIdx.x * 256 + threadIdx.x;
    if (i < 21 * 64) pw_wf[i] = pw_w[i] * dw_w0[i & 63];
    if (i < 21) {
        float s = pw_b[i];
        for (int c = 0; c < 64; ++c) s += pw_w[i * 64 + c] * dw_b0[c];
        pw_bf[i] = s;
    }
}

// ---------------- fully fused branch kernel (R14 structure + T14 prefetch)
// Round-18: async-STAGE split on the pw A-tile — group g+1's global loads
// issue into registers right after group g's As ds_write, flying across
// GEMM1+sampling+GEMM2 (~2000 cyc of cover); after the loop-top barrier
// only ds_writes remain. Cs accesses reverted to unswizzled R14 (R17 showed
// conflicts are off the critical path; swizzle XOR only added VALU).
template<int k>
__global__ __launch_bounds__(256)
void branch_fused_kernel(const float* __restrict__ pw_w, const float* __restrict__ pw_b,
                         const float* __restrict__ dw, const float* __restrict__ inputs,
                         const float* __restrict__ dcn_wt, const float* __restrict__ dcn_b,
                         float* __restrict__ outbuf, int t_slot) {
    constexpr int K = k * k;
    constexpr int TT = NC * K;
    constexpr int pad = k / 2;
    __shared__ float As[64][68];
    __shared__ float Bs[64][68];
    __shared__ float Cs[64][68];
    int nb0 = blockIdx.x * 64;
    int b = nb0 / HWP, p0 = nb0 % HWP;
    int tid = threadIdx.x;
    int tm = (tid & 15) * 4;
    int tn = (tid >> 4) * 4;
    const int m_ = tid & 63;
    const int kq_ = tid >> 6;   // 0..3

    // stage dw tile Bs[kk][px] once
    {
        const float* bp = dw + (size_t)b * CF * HWP + p0;
        for (int i4 = tid; i4 < 64 * 16; i4 += 256) {
            int kk = i4 >> 4, f4 = (i4 & 15) * 4;
            float4 v = *(const float4*)(bp + (size_t)kk * HWP + f4);
            *(float4*)&Bs[kk][f4] = v;
        }
    }

    f32x4 acc0 = 0.f, acc1 = 0.f, acc2 = 0.f, acc3 = 0.f;   // [4ch][4px]
    const float* inb = inputs + (size_t)b * NC * HWP;

    // T14 prefetch registers: this thread's 4 float4 A-staging quota
    float4 a0r, a1r, a2r, a3r;
    // issue loads for group at tap0g (guarded by that group's M)
    {
        int ntapg = (TT < 21) ? TT : 21;
        int Mg = 3 * ntapg;
        if (m_ < Mg) {
            int i = m_ / 3, q = m_ - 3 * i;
            int srow = (q == 2) ? (2 * TT + i) : (2 * i + q);
            const float* ap = pw_w + (size_t)srow * CF;
            a0r = *(const float4*)(ap + (kq_ * 4 + 0) * 4);
            a1r = *(const float4*)(ap + (kq_ * 4 + 1) * 4);
            a2r = *(const float4*)(ap + (kq_ * 4 + 2) * 4);
            a3r = *(const float4*)(ap + (kq_ * 4 + 3) * 4);
        }
    }

    for (int tap0 = 0; tap0 < TT; tap0 += 21) {
        int ntap = (TT - tap0 < 21) ? (TT - tap0) : 21;
        int M = 3 * ntap;
        __syncthreads();   // prior GEMM2 done (As/Cs reads); 1st iter: Bs staged
        // write prefetched A regs -> As[kk][m]
        if (m_ < M) {
            int k0 = kq_ * 16;
            As[k0 + 0][m_] = a0r.x; As[k0 + 1][m_] = a0r.y;
            As[k0 + 2][m_] = a0r.z; As[k0 + 3][m_] = a0r.w;
            As[k0 + 4][m_] = a1r.x; As[k0 + 5][m_] = a1r.y;
            As[k0 + 6][m_] = a1r.z; As[k0 + 7][m_] = a1r.w;
            As[k0 + 8][m_] = a2r.x; As[k0 + 9][m_] = a2r.y;
            As[k0 + 10][m_] = a2r.z; As[k0 + 11][m_] = a2r.w;
            As[k0 + 12][m_] = a3r.x; As[k0 + 13][m_] = a3r.y;
            As[k0 + 14][m_] = a3r.z; As[k0 + 15][m_] = a3r.w;
        }
        // issue next group's loads now; they fly across GEMM1+sample+GEMM2
        {
            int tap0n = tap0 + 21;
            if (tap0n < TT) {
                int ntapn = (TT - tap0n < 21) ? (TT - tap0n) : 21;
                int Mn = 3 * ntapn;
                if (m_ < Mn) {
                    int i = m_ / 3, q = m_ - 3 * i;
                    int r = tap0n + i;
                    int srow = (q == 2) ? (2 * TT + r) : (2 * r + q);
                    const float* ap = pw_w + (size_t)srow * CF;
                    a0r = *(const float4*)(ap + (kq_ * 4 + 0) * 4);
                    a1r = *(const float4*)(ap + (kq_ * 4 + 1) * 4);
                    a2r = *(const float4*)(ap + (kq_ * 4 + 2) * 4);
                    a3r = *(const float4*)(ap + (kq_ * 4 + 3) * 4);
                }
            }
        }
        __syncthreads();
        // GEMM1: C[m][px], K=64
        f32x4 c0 = 0.f, c1 = 0.f, c2 = 0.f, c3 = 0.f;
#pragma unroll 8
        for (int kk = 0; kk < 64; ++kk) {
            f32x4 a = *(const f32x4*)&As[kk][tm];
            f32x4 bv = *(const f32x4*)&Bs[kk][tn];
#pragma unroll
            for (int j = 0; j < 4; ++j) {
                c0[j] += a[0] * bv[j]; c1[j] += a[1] * bv[j];
                c2[j] += a[2] * bv[j]; c3[j] += a[3] * bv[j];
            }
        }
        // park C + bias into Cs (own elements; Cs dead since loop-top sync)
        {
            f32x4 cs[4] = {c0, c1, c2, c3};
#pragma unroll
            for (int r2 = 0; r2 < 4; ++r2) {
                int m = tm + r2;
                if (m < M) {
                    int i = m / 3, q = m - 3 * i;
                    int r = tap0 + i;
                    float bi = pw_b[(q == 2) ? (2 * TT + r) : (2 * r + q)];
                    f32x4 v = cs[r2];
#pragma unroll
                    for (int j = 0; j < 4; ++j) v[j] += bi;
                    *(f32x4*)&Cs[m][tn] = v;
                }
            }
        }
        __syncthreads();
        // (a) stage dcn rows into As (dead after GEMM1); (b) sample in place
        for (int i4 = tid; i4 < ntap * 16; i4 += 256) {
            int row = i4 >> 4, c4 = (i4 & 15) * 4;
            float4 v = *(const float4*)(dcn_wt + (size_t)(tap0 + row) * OO + c4);
            *(float4*)&As[row][c4] = v;
        }
        {
            int px = tid & 63;
            int p = p0 + px;
            int h = p / WW, wq = p % WW;
            for (int i = tid >> 6; i < ntap; i += 4) {
                int r = tap0 + i;
                float oy = Cs[3 * i][px];
                float ox = Cs[3 * i + 1][px];
                float mr = Cs[3 * i + 2][px];
                int c = r / K;
                int kk2 = r - c * K;
                int ky = kk2 / k, kx = kk2 - ky * k;
                const float* inc_ = inb + (size_t)c * HWP;
                float m = 1.f / (1.f + __expf(-mr));
                float py = oy + (float)(ky + h - pad);
                float px_ = ox + (float)(kx + wq - pad);
                float y0 = floorf(py), x0 = floorf(px_);
                float wyf = py - y0, wxf = px_ - x0;
                int iy0 = (int)y0, ix0 = (int)x0;
                bool y0v = (iy0 >= 0) && (iy0 < HH);
                bool y1v = (iy0 + 1 >= 0) && (iy0 + 1 < HH);
                bool x0v = (ix0 >= 0) && (ix0 < WW);
                bool x1v = (ix0 + 1 >= 0) && (ix0 + 1 < WW);
                int yc0 = min(max(iy0, 0), HH - 1), yc1 = min(max(iy0 + 1, 0), HH - 1);
                int xc0 = min(max(ix0, 0), WW - 1), xc1 = min(max(ix0 + 1, 0), WW - 1);
                float v00 = 0.f, v01 = 0.f, v10 = 0.f, v11 = 0.f;
                if (y0v) {
                    if (x0v) v00 = inc_[yc0 * WW + xc0];
                    if (x1v) v01 = inc_[yc0 * WW + xc1];
                }
                if (y1v) {
                    if (x0v) v10 = inc_[yc1 * WW + xc0];
                    if (x1v) v11 = inc_[yc1 * WW + xc1];
                }
                float s = (v00 * (1.f - wyf) * (1.f - wxf) + v01 * (1.f - wyf) * wxf +
                           v10 * wyf * (1.f - wxf) + v11 * wyf * wxf) * m;
                Cs[3 * i][px] = s;   // in-place: sole owner of (i,px)
            }
        }
        __syncthreads();
        // GEMM2: acc[ch][px] += dcn[tap][ch] * s[tap][px]
        for (int kk = 0; kk < ntap; ++kk) {
            f32x4 a = *(const f32x4*)&As[kk][tm];
            f32x4 s = *(const f32x4*)&Cs[3 * kk][tn];
#pragma unroll
            for (int j = 0; j < 4; ++j) {
                acc0[j] += a[0] * s[j]; acc1[j] += a[1] * s[j];
                acc2[j] += a[2] * s[j]; acc3[j] += a[3] * s[j];
            }
        }
    }
    __syncthreads();
    // epilogue: bias+relu, repack into Cs[ch][px], coalesced store
    {
        f32x4 accs[4] = {acc0, acc1, acc2, acc3};
#pragma unroll
        for (int r2 = 0; r2 < 4; ++r2) {
            int ch = tm + r2;
            float bi = dcn_b[ch];
            f32x4 v = accs[r2];
#pragma unroll
            for (int j = 0; j < 4; ++j) {
                v[j] += bi;
                v[j] = v[j] > 0.f ? v[j] : 0.f;
            }
            *(f32x4*)&Cs[ch][tn] = v;
        }
    }
    __syncthreads();
    {
        float* op = outbuf + (size_t)((b * 3 + t_slot) * OO) * HWP + p0;
        for (int i4 = tid; i4 < 64 * 16; i4 += 256) {
            int row = i4 >> 4, f4 = (i4 & 15) * 4;
            *(float4*)(op + (size_t)row * HWP + f4) = *(const float4*)&Cs[row][f4];
        }
    }
}

// ---------------- attention GEMM, KC=32 LDS chunks ------------------------
__global__ __launch_bounds__(256)
void attn_gemm_kernel(const float* __restrict__ outbuf, const float* __restrict__ attn_wt,
                      const float* __restrict__ attn_b, float* __restrict__ partial) {
    __shared__ float As[32][68];
    __shared__ float Bs[32][132];
    __shared__ float red[16][68];
    int nb0 = blockIdx.x * 128;
    int b = nb0 / HWP, p0 = nb0 % HWP;
    int tid = threadIdx.x;
    int tm = (tid & 15) * 4;
    int tn = (tid >> 4) * 8;

    f32x4 aA0 = 0.f, aA1 = 0.f, aB0 = 0.f, aB1 = 0.f;
    f32x4 aC0 = 0.f, aC1 = 0.f, aD0 = 0.f, aD1 = 0.f;
    for (int kc = 0; kc < 6; ++kc) {
        for (int i4 = tid; i4 < 32 * 16; i4 += 256) {
            int row = i4 >> 4, c4 = (i4 & 15) * 4;
            float4 v = *(const float4*)(attn_wt + (size_t)(kc * 32 + row) * OO + c4);
            As[row][c4] = v.x; As[row][c4 + 1] = v.y; As[row][c4 + 2] = v.z; As[row][c4 + 3] = v.w;
        }
        const float* bp = outbuf + ((size_t)(b * 192 + kc * 32)) * HWP + p0;
        for (int i4 = tid; i4 < 32 * 32; i4 += 256) {
            int row = i4 >> 5, f4 = (i4 & 31) * 4;
            float4 v = *(const float4*)(bp + (size_t)row * HWP + f4);
            *(float4*)&Bs[row][f4] = v;
        }
        __syncthreads();
#pragma unroll 4
        for (int kk = 0; kk < 32; ++kk) {
            f32x4 a  = *(const f32x4*)&As[kk][tm];
            f32x4 b0 = *(const f32x4*)&Bs[kk][tn];
            f32x4 b1 = *(const f32x4*)&Bs[kk][tn + 4];
#pragma unroll
            for (int j = 0; j < 4; ++j) {
                aA0[j] += a[0] * b0[j];  aA1[j] += a[0] * b1[j];
                aB0[j] += a[1] * b0[j];  aB1[j] += a[1] * b1[j];
                aC0[j] += a[2] * b0[j];  aC1[j] += a[2] * b1[j];
                aD0[j] += a[3] * b0[j];  aD1[j] += a[3] * b1[j];
            }
        }
        __syncthreads();
    }
    float bsum[4];
    {
        f32x4 accs[8] = {aA0, aA1, aB0, aB1, aC0, aC1, aD0, aD1};
#pragma unroll
        for (int row = 0; row < 4; ++row) {
            float bi = attn_b[tm + row];
            float s = 0.f;
#pragma unroll
            for (int j = 0; j < 4; ++j) {
                float v0 = accs[row * 2][j] + bi;
                float v1 = accs[row * 2 + 1][j] + bi;
                s += (v0 > 0.f ? v0 : 0.f) + (v1 > 0.f ? v1 : 0.f);
            }
            bsum[row] = s;
        }
    }
    int pg = tid >> 4;
#pragma unroll
    for (int row = 0; row < 4; ++row) red[pg][tm + row] = bsum[row];
    __syncthreads();
    if (tid < 64) {
        float s = 0.f;
#pragma unroll
        for (int g = 0; g < 16; ++g) s += red[g][tid];
        int lb = p0 / 128;
        partial[((size_t)(b * PBLK2 + lb)) * OO + tid] = s;
    }
}

// ---------------- attention finish ----------------
__global__ void attn_finish_kernel(const float* __restrict__ partial,
                                   const float* __restrict__ fc_w, const float* __restrict__ fc_b,
                                   const float* __restrict__ fcs_w0, const float* __restrict__ fcs_b0,
                                   const float* __restrict__ fcs_w1, const float* __restrict__ fcs_b1,
                                   const float* __restrict__ fcs_w2, const float* __restrict__ fcs_b2,
                                   float* __restrict__ atts) {
    int b = blockIdx.x;
    __shared__ float attm[OO];
    __shared__ float fcv[32];
    int tid = threadIdx.x;
    if (tid < OO) {
        float s = 0.f;
        for (int blk = 0; blk < PBLK2; ++blk)
            s += partial[((size_t)(b * PBLK2 + blk)) * OO + tid];
        attm[tid] = s / (float)HWP;
    }
    __syncthreads();
    if (tid < 32) {
        float s = fc_b[tid];
        for (int o = 0; o < OO; ++o) s += fc_w[tid * OO + o] * attm[o];
        fcv[tid] = s > 0.f ? s : 0.f;
    }
    __syncthreads();
    if (tid < OO) {
        {
            float s = fcs_b0[tid];
            for (int j = 0; j < 32; ++j) s += fcs_w0[tid * 32 + j] * fcv[j];
            atts[b * 192 + 0 * OO + tid] = s;
        }
        {
            float s = fcs_b1[tid];
            for (int j = 0; j < 32; ++j) s += fcs_w1[tid * 32 + j] * fcv[j];
            atts[b * 192 + 1 * OO + tid] = s;
        }
        {
            float s = fcs_b2[tid];
            for (int j = 0; j < 32; ++j) s += fcs_w2[tid * 32 + j] * fcv[j];
            atts[b * 192 + 2 * OO + tid] = s;
        }
    }
}

// ---------------- final GEMM, KC=32 LDS chunks ----------------------------
__global__ __launch_bounds__(256)
void final_gemm_kernel(const float* __restrict__ outbuf, const float* __restrict__ atts,
                       const float* __restrict__ conv_wt, const float* __restrict__ conv_b,
                       float* __restrict__ out) {
    __shared__ float As[32][68];
    __shared__ float Bs[32][132];
    int nb0 = blockIdx.x * 128;
    int b = nb0 / HWP, p0 = nb0 % HWP;
    int tid = threadIdx.x;
    int tm = (tid & 15) * 4;
    int tn = (tid >> 4) * 8;
    const float* at = atts + b * 192;

    f32x4 aA0 = 0.f, aA1 = 0.f, aB0 = 0.f, aB1 = 0.f;
    f32x4 aC0 = 0.f, aC1 = 0.f, aD0 = 0.f, aD1 = 0.f;
    for (int kc = 0; kc < 6; ++kc) {
        for (int i4 = tid; i4 < 32 * 16; i4 += 256) {
            int row = i4 >> 4, c4 = (i4 & 15) * 4;
            float4 v = *(const float4*)(conv_wt + (size_t)(kc * 32 + row) * OO + c4);
            As[row][c4] = v.x; As[row][c4 + 1] = v.y; As[row][c4 + 2] = v.z; As[row][c4 + 3] = v.w;
        }
        const float* bp = outbuf + ((size_t)(b * 192 + kc * 32)) * HWP + p0;
        for (int i4 = tid; i4 < 32 * 32; i4 += 256) {
            int row = i4 >> 5, f4 = (i4 & 31) * 4;
            float sc = at[kc * 32 + row];
            float4 v = *(const float4*)(bp + (size_t)row * HWP + f4);
            Bs[row][f4] = v.x * sc; Bs[row][f4 + 1] = v.y * sc;
            Bs[row][f4 + 2] = v.z * sc; Bs[row][f4 + 3] = v.w * sc;
        }
        __syncthreads();
#pragma unroll 4
        for (int kk = 0; kk < 32; ++kk) {
            f32x4 a  = *(const f32x4*)&As[kk][tm];
            f32x4 b0 = *(const f32x4*)&Bs[kk][tn];
            f32x4 b1 = *(const f32x4*)&Bs[kk][tn + 4];
#pragma unroll
            for (int j = 0; j < 4; ++j) {
                aA0[j] += a[0] * b0[j];  aA1[j] += a[0] * b1[j];
                aB0[j] += a[1] * b0[j];  aB1[j] += a[1] * b1[j];
                aC0[j] += a[2] * b0[j];  aC1[j] += a[2] * b1[j];
                aD0[j] += a[3] * b0[j];  aD1[j] += a[3] * b1[j];
            }
        }
        __syncthreads();
    }
    f32x4 accs[8] = {aA0, aA1, aB0, aB1, aC0, aC1, aD0, aD1};
#pragma unroll
    for (int row = 0; row < 4; ++row) {
        int ch = tm + row;
        float bi = conv_b[ch];
        float* ptr = out + ((size_t)(b * OO + ch)) * HWP + p0 + tn;
        f32x4 lo = accs[row * 2], hi = accs[row * 2 + 1];
#pragma unroll
        for (int j = 0; j < 4; ++j) {
            lo[j] += bi; hi[j] += bi;
            lo[j] = lo[j] > 0.f ? lo[j] : 0.f;
            hi[j] = hi[j] > 0.f ? hi[j] : 0.f;
        }
        *(f32x4*)ptr = lo;
        *(f32x4*)(ptr + 4) = hi;
    }
}

extern "C" void kernel_launch(void* const* d_in, const int* in_sizes, int n_in,
                              void* d_out, int out_size, void* d_ws, size_t ws_size,
                              hipStream_t stream) {
    const float* fea    = (const float*)d_in[0];
    const float* inputs = (const float*)d_in[1];
    const float* dw_w[3]  = {(const float*)d_in[2],  (const float*)d_in[8],  (const float*)d_in[14]};
    const float* dw_b[3]  = {(const float*)d_in[3],  (const float*)d_in[9],  (const float*)d_in[15]};
    const float* pw_w[3]  = {(const float*)d_in[4],  (const float*)d_in[10], (const float*)d_in[16]};
    const float* pw_b[3]  = {(const float*)d_in[5],  (const float*)d_in[11], (const float*)d_in[17]};
    const float* dcn_w[3] = {(const float*)d_in[6],  (const float*)d_in[12], (const float*)d_in[18]};
    const float* dcn_b[3] = {(const float*)d_in[7],  (const float*)d_in[13], (const float*)d_in[19]};
    const float* attn_w = (const float*)d_in[20];
    const float* attn_b = (const float*)d_in[21];
    const float* fc_w   = (const float*)d_in[22];
    const float* fc_b   = (const float*)d_in[23];
    const float* fcs_w[3] = {(const float*)d_in[24], (const float*)d_in[26], (const float*)d_in[28]};
    const float* fcs_b[3] = {(const float*)d_in[25], (const float*)d_in[27], (const float*)d_in[29]};
    const float* conv_w = (const float*)d_in[30];
    const float* conv_b = (const float*)d_in[31];
    float* out = (float*)d_out;

    const size_t F_OUTBUF = (size_t)BB * 3 * OO * HWP;   // 28,311,552
    float* W = (float*)d_ws;
    float* outbuf = W;            W += F_OUTBUF;
    float* partial = W;           W += 73728;    // BB*PBLK2*64
    float* atts = W;              W += 768;
    float* dcn_wt0 = W;           W += 512;
    float* dcn_wt1 = W;           W += 4096;
    float* dcn_wt2 = W;           W += 11264;
    float* attn_wt = W;           W += 12288;
    float* conv_wt = W;           W += 12288;
    float* pw_wf = W;             W += 1344;     // folded k1 pw weights (21x64)
    float* pw_bf = W;             W += 32;       // folded k1 bias (21)
    float* dwscr = out;           // d_out as dw-plane scratch; final_gemm rewrites d_out

    transpose_kernel<<<(192 * 64 + 255) / 256, 256, 0, stream>>>(attn_w, attn_wt, 64, 192);
    transpose_kernel<<<(192 * 64 + 255) / 256, 256, 0, stream>>>(conv_w, conv_wt, 64, 192);
    transpose_kernel<<<(7 * 64 + 255) / 256, 256, 0, stream>>>(dcn_w[0], dcn_wt0, 64, 7);
    transpose_kernel<<<(63 * 64 + 255) / 256, 256, 0, stream>>>(dcn_w[1], dcn_wt1, 64, 63);
    transpose_kernel<<<(175 * 64 + 255) / 256, 256, 0, stream>>>(dcn_w[2], dcn_wt2, 64, 175);
    k1_fold_kernel<<<(21 * 64 + 255) / 256, 256, 0, stream>>>(pw_w[0], pw_b[0],
                                                              dw_w[0], dw_b[0], pw_wf, pw_bf);

    const int dwv_grid = (BB * CF * HH * 48) / 256;   // 9216
    const int fuse_grid = NTOT / 64;                  // 2304

    // ---- k=5 branch ----
    dwv_kernel<5><<<dwv_grid, 256, 0, stream>>>(fea, dw_w[2], dw_b[2], dwscr);
    branch_fused_kernel<5><<<fuse_grid, 256, 0, stream>>>(
        pw_w[2], pw_b[2], dwscr, inputs, dcn_wt2, dcn_b[2], outbuf, 2);
    // ---- k=3 branch ----
    dwv_kernel<3><<<dwv_grid, 256, 0, stream>>>(fea, dw_w[1], dw_b[1], dwscr);
    branch_fused_kernel<3><<<fuse_grid, 256, 0, stream>>>(
        pw_w[1], pw_b[1], dwscr, inputs, dcn_wt1, dcn_b[1], outbuf, 1);
    // ---- k=1 branch: folded weights, B operand = fea directly ----
    branch_fused_kernel<1><<<fuse_grid, 256, 0, stream>>>(
        pw_wf, pw_bf, fea, inputs, dcn_wt0, dcn_b[0], outbuf, 0);

    // ---- attention + final (tiled GEMMs, KC=32) ----
    attn_gemm_kernel<<<NTOT / 128, 256, 0, stream>>>(outbuf, attn_wt, attn_b, partial);
    attn_finish_kernel<<<BB, 64, 0, stream>>>(partial, fc_w, fc_b,
                                              fcs_w[0], fcs_b[0], fcs_w[1], fcs_b[1],
                                              fcs_w[2], fcs_b[2], atts);
    final_gemm_kernel<<<NTOT / 128, 256, 0, stream>>>(outbuf, atts, conv_wt, conv_b, out);
}